// Round 1
// baseline (903.057 us; speedup 1.0000x reference)
//
#include <hip/hip_runtime.h>

typedef __attribute__((ext_vector_type(8))) __bf16 bf16x8;
typedef __attribute__((ext_vector_type(8))) short s16x8;
typedef __attribute__((ext_vector_type(4))) float f32x4;

__device__ __forceinline__ unsigned short f2bf(float f) {
  unsigned int u = __float_as_uint(f);
  u += 0x7FFFu + ((u >> 16) & 1u);   // RNE
  return (unsigned short)(u >> 16);
}

__device__ __forceinline__ void gload_lds16(const void* g, void* l) {
  __builtin_amdgcn_global_load_lds(
      (const __attribute__((address_space(1))) void*)g,
      (__attribute__((address_space(3))) void*)l, 16, 0, 0);
}

// ---------------- conversion kernels (fast path) ----------------

__global__ __launch_bounds__(256) void convert_a_kernel(
    const float* __restrict__ in, unsigned short* __restrict__ out, size_t n8) {
  size_t i = (size_t)blockIdx.x * blockDim.x + threadIdx.x;
  size_t stride = (size_t)gridDim.x * blockDim.x;
  for (; i < n8; i += stride) {
    const float4* p = (const float4*)in + 2 * i;
    float4 f0 = p[0], f1 = p[1];
    s16x8 v = {(short)f2bf(f0.x), (short)f2bf(f0.y), (short)f2bf(f0.z), (short)f2bf(f0.w),
               (short)f2bf(f1.x), (short)f2bf(f1.y), (short)f2bf(f1.z), (short)f2bf(f1.w)};
    *((s16x8*)out + i) = v;
  }
}

// wt[n][k] = w[k][n], fp32 -> bf16
__global__ __launch_bounds__(256) void transpose_w_kernel(
    const float* __restrict__ w, unsigned short* __restrict__ wt, int N) {
  __shared__ float tile[32][33];
  int bx = blockIdx.x, by = blockIdx.y;
  int tx = threadIdx.x & 31, ty = threadIdx.x >> 5;  // ty in 0..7
#pragma unroll
  for (int i = 0; i < 4; ++i)
    tile[ty + 8 * i][tx] = w[(size_t)(by * 32 + ty + 8 * i) * N + bx * 32 + tx];
  __syncthreads();
#pragma unroll
  for (int i = 0; i < 4; ++i)
    wt[(size_t)(bx * 32 + ty + 8 * i) * N + by * 32 + tx] = f2bf(tile[tx][ty + 8 * i]);
}

// ---------------- GEMM: X[M][N] = A[M][K] * B[K][N], B given as BT[n][k] ----
// 128x128 tile, BK=32, 4 waves (2x2), each wave 64x64 via 4x4 frags of
// v_mfma_f32_16x16x32_bf16. Double-buffered LDS. XOR chunk-swizzle
// (slot s holds global k-chunk s ^ (row&3)) applied on BOTH sides.

template <bool F32IN>
__global__ __launch_bounds__(256) void gemm_kernel(
    const void* __restrict__ Ap, const void* __restrict__ Bp,
    float* __restrict__ X, int M, int N, int K) {
  __shared__ __align__(16) unsigned short ldsA[2][128 * 32];
  __shared__ __align__(16) unsigned short ldsB[2][128 * 32];

  const int nbx = N >> 7;
  int wg = blockIdx.x;
  int nwg = gridDim.x;
  int cpx = nwg >> 3;                       // nwg divisible by 8
  int swz = (wg & 7) * cpx + (wg >> 3);     // XCD-aware bijective swizzle
  int by = swz / nbx, bx = swz - by * nbx;
  size_t m0 = (size_t)by << 7;
  size_t n0 = (size_t)bx << 7;

  int tid = threadIdx.x;
  int lane = tid & 63;
  int wid = tid >> 6;
  int wrow = (wid >> 1) * 64;
  int wcol = (wid & 1) * 64;

  f32x4 acc[4][4];
#pragma unroll
  for (int m = 0; m < 4; ++m)
#pragma unroll
    for (int n = 0; n < 4; ++n) acc[m][n] = f32x4{0.f, 0.f, 0.f, 0.f};

  const int nk = K >> 5;

  // shared compute: ds_read frags (swizzled) + 16 MFMA
  auto compute = [&](int cur) {
    bf16x8 af[4], bfr[4];
    int kc = (lane >> 4) ^ (lane & 3);  // (row&3) == (lane&3) since wrow,m*16 are mult of 4
#pragma unroll
    for (int m = 0; m < 4; ++m) {
      int row = wrow + m * 16 + (lane & 15);
      af[m] = *(const bf16x8*)&ldsA[cur][row * 32 + kc * 8];
    }
#pragma unroll
    for (int n = 0; n < 4; ++n) {
      int col = wcol + n * 16 + (lane & 15);
      bfr[n] = *(const bf16x8*)&ldsB[cur][col * 32 + kc * 8];
    }
#pragma unroll
    for (int m = 0; m < 4; ++m)
#pragma unroll
      for (int n = 0; n < 4; ++n)
        acc[m][n] = __builtin_amdgcn_mfma_f32_16x16x32_bf16(af[m], bfr[n], acc[m][n], 0, 0, 0);
  };

  if constexpr (!F32IN) {
    const unsigned short* A16 = (const unsigned short*)Ap;  // [M][K] bf16
    const unsigned short* B16 = (const unsigned short*)Bp;  // [N][K] bf16 (w^T)
    auto stage = [&](int buf, int kt) {
#pragma unroll
      for (int r = 0; r < 2; ++r) {
        int c = (r << 8) + tid;
        int row = c >> 2, g = c & 3;
        int ks = (g ^ (row & 3)) << 3;  // pre-swizzled global source chunk
        int ldsbase = ((r << 8) + (wid << 6)) << 3;  // wave-uniform, elems
        gload_lds16(A16 + (m0 + row) * (size_t)K + kt + ks, &ldsA[buf][ldsbase]);
        gload_lds16(B16 + (n0 + row) * (size_t)K + kt + ks, &ldsB[buf][ldsbase]);
      }
    };
    stage(0, 0);
    __syncthreads();  // drains vmcnt before barrier
    for (int t = 0; t < nk; ++t) {
      int cur = t & 1;
      if (t + 1 < nk) stage(cur ^ 1, (t + 1) << 5);
      compute(cur);
      __syncthreads();
    }
  } else {
    const float* A32 = (const float*)Ap;  // [M][K] fp32
    const float* W32 = (const float*)Bp;  // [K][N] fp32
    float4 aq[2][2];
    float bq[2][8];
    auto loadregs = [&](int kt) {
#pragma unroll
      for (int r = 0; r < 2; ++r) {
        int c = (r << 8) + tid;
        int row = c >> 2, g = c & 3;
        const float4* pa = (const float4*)(A32 + (m0 + row) * (size_t)K + kt + g * 8);
        aq[r][0] = pa[0];
        aq[r][1] = pa[1];
        const float* pb = W32 + (size_t)(kt + g * 8) * N + n0 + row;
#pragma unroll
        for (int i = 0; i < 8; ++i) bq[r][i] = pb[(size_t)i * N];
      }
    };
    auto writelds = [&](int buf) {
#pragma unroll
      for (int r = 0; r < 2; ++r) {
        int c = (r << 8) + tid;
        int row = c >> 2, g = c & 3;
        int s = g ^ (row & 3);
        s16x8 va = {(short)f2bf(aq[r][0].x), (short)f2bf(aq[r][0].y),
                    (short)f2bf(aq[r][0].z), (short)f2bf(aq[r][0].w),
                    (short)f2bf(aq[r][1].x), (short)f2bf(aq[r][1].y),
                    (short)f2bf(aq[r][1].z), (short)f2bf(aq[r][1].w)};
        s16x8 vb = {(short)f2bf(bq[r][0]), (short)f2bf(bq[r][1]),
                    (short)f2bf(bq[r][2]), (short)f2bf(bq[r][3]),
                    (short)f2bf(bq[r][4]), (short)f2bf(bq[r][5]),
                    (short)f2bf(bq[r][6]), (short)f2bf(bq[r][7])};
        *(s16x8*)&ldsA[buf][row * 32 + s * 8] = va;
        *(s16x8*)&ldsB[buf][row * 32 + s * 8] = vb;
      }
    };
    loadregs(0);
    writelds(0);
    __syncthreads();
    for (int t = 0; t < nk; ++t) {
      int cur = t & 1;
      if (t + 1 < nk) loadregs((t + 1) << 5);  // issue early: latency under MFMA
      compute(cur);
      if (t + 1 < nk) writelds(cur ^ 1);
      __syncthreads();
    }
  }

  // epilogue: C/D layout col = lane&15, row = (lane>>4)*4 + j  [m89-verified]
#pragma unroll
  for (int m = 0; m < 4; ++m) {
    size_t row = m0 + wrow + m * 16 + ((lane >> 4) << 2);
#pragma unroll
    for (int n = 0; n < 4; ++n) {
      size_t col = n0 + wcol + n * 16 + (lane & 15);
      float* px = X + row * (size_t)N + col;
#pragma unroll
      for (int j = 0; j < 4; ++j) px[(size_t)j * N] = acc[m][n][j];
    }
  }
}

// ---------------- LIF scan: in-place X -> spikes ----------------
// v' = decay*(v-REST)+REST; +x if refrac<=0; refrac=max(refrac-1,0);
// s = v>=-52; refrac=5,v=-65 on spike.  One thread per (b,n) column.

__global__ __launch_bounds__(256) void lif_scan_kernel(
    float* __restrict__ XS, int T, int stride) {
  int idx = blockIdx.x * 256 + threadIdx.x;
  const float decay = 0.99004983374916811f;  // exp(-1/100) in fp32
  float v = -65.0f, refrac = 0.0f;
  size_t p = (size_t)idx;
  for (int t0 = 0; t0 < T; t0 += 8) {
    float x[8];
#pragma unroll
    for (int i = 0; i < 8; ++i) x[i] = XS[p + (size_t)i * stride];  // batch loads
    float o[8];
#pragma unroll
    for (int i = 0; i < 8; ++i) {
      v = decay * (v + 65.0f) - 65.0f;
      if (refrac <= 0.0f) v += x[i];
      refrac = fmaxf(refrac - 1.0f, 0.0f);
      bool s = (v >= -52.0f);
      o[i] = s ? 1.0f : 0.0f;
      refrac = s ? 5.0f : refrac;
      v = s ? -65.0f : v;
    }
#pragma unroll
    for (int i = 0; i < 8; ++i) XS[p + (size_t)i * stride] = o[i];
    p += (size_t)8 * stride;
  }
}

// ---------------- launch ----------------

extern "C" void kernel_launch(void* const* d_in, const int* in_sizes, int n_in,
                              void* d_out, int out_size, void* d_ws, size_t ws_size,
                              hipStream_t stream) {
  const float* input = (const float*)d_in[0];  // [T,B,N] fp32
  const float* w = (const float*)d_in[1];      // [N,N] fp32
  const int N = 4096;
  const int T = 512;
  const int B = 32;
  const int M = T * B;  // 16384
  float* X = (float*)d_out;

  size_t a_bytes = (size_t)M * N * 2;       // 128 MiB
  size_t w_bytes = (size_t)N * N * 2;       // 32 MiB
  int ngrid = (M / 128) * (N / 128);        // 4096

  if (ws_size >= a_bytes + w_bytes) {
    unsigned short* A16 = (unsigned short*)d_ws;
    unsigned short* WT16 = (unsigned short*)((char*)d_ws + a_bytes);
    hipLaunchKernelGGL(convert_a_kernel, dim3(2048), dim3(256), 0, stream,
                       input, A16, (size_t)M * N / 8);
    hipLaunchKernelGGL(transpose_w_kernel, dim3(N / 32, N / 32), dim3(256), 0, stream,
                       w, WT16, N);
    hipLaunchKernelGGL(gemm_kernel<false>, dim3(ngrid), dim3(256), 0, stream,
                       (const void*)A16, (const void*)WT16, X, M, N, N);
  } else {
    hipLaunchKernelGGL(gemm_kernel<true>, dim3(ngrid), dim3(256), 0, stream,
                       (const void*)input, (const void*)w, X, M, N, N);
  }
  hipLaunchKernelGGL(lif_scan_kernel, dim3((B * N) / 256), dim3(256), 0, stream,
                     X, T, B * N);
}

// Round 2
// 725.955 us; speedup vs baseline: 1.2440x; 1.2440x over previous
//
#include <hip/hip_runtime.h>

typedef __attribute__((ext_vector_type(8))) __bf16 bf16x8;
typedef __attribute__((ext_vector_type(8))) short s16x8;
typedef __attribute__((ext_vector_type(4))) float f32x4;
typedef unsigned short ushort_t;

__device__ __forceinline__ unsigned short f2bf(float f) {
  unsigned int u = __float_as_uint(f);
  u += 0x7FFFu + ((u >> 16) & 1u);  // RNE
  return (unsigned short)(u >> 16);
}

__device__ __forceinline__ void gload_lds16(const void* g, void* l) {
  __builtin_amdgcn_global_load_lds(
      (const __attribute__((address_space(1))) void*)g,
      (__attribute__((address_space(3))) void*)l, 16, 0, 0);
}

// raw barrier: no implicit vmcnt(0) drain (unlike __syncthreads)
__device__ __forceinline__ void bar() {
  __builtin_amdgcn_sched_barrier(0);
  asm volatile("" ::: "memory");
  __builtin_amdgcn_s_barrier();
  asm volatile("" ::: "memory");
  __builtin_amdgcn_sched_barrier(0);
}

// ---------------- conversion kernels ----------------

__global__ __launch_bounds__(256) void convert_a_kernel(
    const float* __restrict__ in, unsigned short* __restrict__ out, size_t n8) {
  size_t i = (size_t)blockIdx.x * blockDim.x + threadIdx.x;
  size_t stride = (size_t)gridDim.x * blockDim.x;
  for (; i < n8; i += stride) {
    const float4* p = (const float4*)in + 2 * i;
    float4 f0 = p[0], f1 = p[1];
    s16x8 v = {(short)f2bf(f0.x), (short)f2bf(f0.y), (short)f2bf(f0.z), (short)f2bf(f0.w),
               (short)f2bf(f1.x), (short)f2bf(f1.y), (short)f2bf(f1.z), (short)f2bf(f1.w)};
    *((s16x8*)out + i) = v;
  }
}

// wt[n][k] = w[k][n], fp32 -> bf16
__global__ __launch_bounds__(256) void transpose_w_kernel(
    const float* __restrict__ w, unsigned short* __restrict__ wt, int N) {
  __shared__ float tile[32][33];
  int bx = blockIdx.x, by = blockIdx.y;
  int tx = threadIdx.x & 31, ty = threadIdx.x >> 5;
#pragma unroll
  for (int i = 0; i < 4; ++i)
    tile[ty + 8 * i][tx] = w[(size_t)(by * 32 + ty + 8 * i) * N + bx * 32 + tx];
  __syncthreads();
#pragma unroll
  for (int i = 0; i < 4; ++i)
    wt[(size_t)(bx * 32 + ty + 8 * i) * N + by * 32 + tx] = f2bf(tile[tx][ty + 8 * i]);
}

// ---------------- GEMM 256x256, BK=64, 8 waves, 8-phase counted-vmcnt ------
// X[M][N] = A[M][K] * B[K][N] with B given as BT[n][k] (bf16 both).
// LDS: per operand a 4-deep ring of K-half slots [256 rows][32 k] bf16 (16KB).
// K-half H = 2*t + ks. Tile t reads slots {2(t&1), 2(t&1)+1}.
// Phases per tile: p0:(ks0,mh0) p1:(ks0,mh1) p2:(ks1,mh0) p3:(ks1,mh1).
// Staging: p0 -> A(2t+3),B(2t+3); p2 -> A(2t+4); p3 -> B(2t+4).
// Boundary: vmcnt(4) (vmcnt(0) into last tile). Swizzle: chunk p = c ^ ((r>>1)&3).

__global__ __launch_bounds__(512, 2) void gemm256_kernel(
    const unsigned short* __restrict__ A, const unsigned short* __restrict__ Bt,
    float* __restrict__ X, int M, int N, int K) {
  __shared__ __align__(16) unsigned short Ar[4][256 * 32];
  __shared__ __align__(16) unsigned short Br[4][256 * 32];

  const int nbx = N >> 8;
  int wg = blockIdx.x;
  int nwg = gridDim.x;
  int cpx = nwg >> 3;                    // nwg % 8 == 0 (1024)
  int swz = (wg & 7) * cpx + (wg >> 3);  // XCD-aware bijective swizzle
  int by = swz / nbx, bx = swz - by * nbx;
  size_t m0 = (size_t)by << 8;
  size_t n0 = (size_t)bx << 8;

  int tid = threadIdx.x;
  int lane = tid & 63;
  int wid = tid >> 6;
  int wm = wid >> 2;   // 0..1 -> A rows wm*128..+127
  int wn = wid & 3;    // 0..3 -> B rows (C cols) wn*64..+63

  f32x4 acc[8][4];
#pragma unroll
  for (int m = 0; m < 8; ++m)
#pragma unroll
    for (int n = 0; n < 4; ++n) acc[m][n] = f32x4{0.f, 0.f, 0.f, 0.f};

  const int nk = K >> 6;  // BK=64 tiles

  // ---- staging: one K-half (256x32) = 512 threads x 2 x 16B ----
  auto stageA = [&](int H) {
    int slot = H & 3;
    int kbase = ((H >> 1) << 6) + ((H & 1) << 5);
#pragma unroll
    for (int i = 0; i < 2; ++i) {
      int s = tid + (i << 9);
      int r = s >> 2, pch = s & 3;
      int c = pch ^ ((r >> 1) & 3);
      gload_lds16(A + (m0 + r) * (size_t)K + kbase + c * 8,
                  &Ar[slot][(size_t)((wid << 6) + (i << 9)) * 8]);
    }
  };
  auto stageB = [&](int H) {
    int slot = H & 3;
    int kbase = ((H >> 1) << 6) + ((H & 1) << 5);
#pragma unroll
    for (int i = 0; i < 2; ++i) {
      int s = tid + (i << 9);
      int r = s >> 2, pch = s & 3;
      int c = pch ^ ((r >> 1) & 3);
      gload_lds16(Bt + (n0 + r) * (size_t)K + kbase + c * 8,
                  &Br[slot][(size_t)((wid << 6) + (i << 9)) * 8]);
    }
  };

  bf16x8 af[4], bf[4];
  auto rdA = [&](int slot, int mh) {
#pragma unroll
    for (int m = 0; m < 4; ++m) {
      int r = wm * 128 + (mh * 4 + m) * 16 + (lane & 15);
      int p = (lane >> 4) ^ ((r >> 1) & 3);
      af[m] = *(const bf16x8*)&Ar[slot][r * 32 + p * 8];
    }
  };
  auto rdB = [&](int slot) {
#pragma unroll
    for (int n = 0; n < 4; ++n) {
      int r = wn * 64 + n * 16 + (lane & 15);
      int p = (lane >> 4) ^ ((r >> 1) & 3);
      bf[n] = *(const bf16x8*)&Br[slot][r * 32 + p * 8];
    }
  };
  auto quad = [&](int mh) {
    asm volatile("s_waitcnt lgkmcnt(0)" ::: "memory");
    __builtin_amdgcn_sched_barrier(0);
    __builtin_amdgcn_s_setprio(1);
#pragma unroll
    for (int m = 0; m < 4; ++m)
#pragma unroll
      for (int n = 0; n < 4; ++n)
        acc[mh * 4 + m][n] =
            __builtin_amdgcn_mfma_f32_16x16x32_bf16(af[m], bf[n], acc[mh * 4 + m][n], 0, 0, 0);
    __builtin_amdgcn_s_setprio(0);
  };

  // ---- prologue: halves 0,1 (tile 0) + 2 (tile 1 first half) ----
  stageA(0); stageB(0); stageA(1); stageB(1); stageA(2); stageB(2);
  asm volatile("s_waitcnt vmcnt(4)" ::: "memory");  // halves 0,1 landed; 2 in flight
  bar();

  for (int t = 0; t < nk; ++t) {
    int db = t & 1;
    int s0 = db << 1, s1 = (db << 1) | 1;
    // p0: ks=0, mh=0
    rdA(s0, 0);
    rdB(s0);
    if (t + 1 < nk) { stageA(2 * t + 3); stageB(2 * t + 3); }
    quad(0);
    bar();
    // p1: ks=0, mh=1
    rdA(s0, 1);
    quad(1);
    bar();
    // p2: ks=1, mh=0  (slot s0 now free -> stage A half 2t+4 into it)
    rdA(s1, 0);
    rdB(s1);
    if (t + 2 < nk) stageA(2 * t + 4);
    quad(0);
    bar();
    // p3: ks=1, mh=1
    rdA(s1, 1);
    if (t + 2 < nk) stageB(2 * t + 4);
    quad(1);
    if (t + 1 < nk) {
      if (t + 2 >= nk)
        asm volatile("s_waitcnt vmcnt(0)" ::: "memory");
      else
        asm volatile("s_waitcnt vmcnt(4)" ::: "memory");
      bar();
    }
  }

  // epilogue: C/D frag layout col=lane&15, row=(lane>>4)*4+j
#pragma unroll
  for (int m = 0; m < 8; ++m) {
    size_t row = m0 + wm * 128 + m * 16 + ((lane >> 4) << 2);
#pragma unroll
    for (int n = 0; n < 4; ++n) {
      size_t col = n0 + wn * 64 + n * 16 + (lane & 15);
      float* px = X + row * (size_t)N + col;
#pragma unroll
      for (int j = 0; j < 4; ++j) px[(size_t)j * N] = acc[m][n][j];
    }
  }
}

// ---------------- LIF scan: in-place X -> spikes ----------------

__global__ __launch_bounds__(256) void lif_scan_kernel(
    float* __restrict__ XS, int T, int stride) {
  int idx = blockIdx.x * 256 + threadIdx.x;
  const float decay = 0.99004983374916811f;  // exp(-1/100) fp32
  float v = -65.0f, refrac = 0.0f;
  size_t p = (size_t)idx;
  for (int t0 = 0; t0 < T; t0 += 8) {
    float x[8];
#pragma unroll
    for (int i = 0; i < 8; ++i) x[i] = XS[p + (size_t)i * stride];
    float o[8];
#pragma unroll
    for (int i = 0; i < 8; ++i) {
      v = decay * (v + 65.0f) - 65.0f;
      if (refrac <= 0.0f) v += x[i];
      refrac = fmaxf(refrac - 1.0f, 0.0f);
      bool s = (v >= -52.0f);
      o[i] = s ? 1.0f : 0.0f;
      refrac = s ? 5.0f : refrac;
      v = s ? -65.0f : v;
    }
#pragma unroll
    for (int i = 0; i < 8; ++i) XS[p + (size_t)i * stride] = o[i];
    p += (size_t)8 * stride;
  }
}

// ---------------- launch ----------------

extern "C" void kernel_launch(void* const* d_in, const int* in_sizes, int n_in,
                              void* d_out, int out_size, void* d_ws, size_t ws_size,
                              hipStream_t stream) {
  const float* input = (const float*)d_in[0];  // [T,B,N] fp32
  const float* w = (const float*)d_in[1];      // [N,N] fp32
  const int N = 4096, T = 512, B = 32;
  const int M = T * B;  // 16384
  float* X = (float*)d_out;

  size_t a_bytes = (size_t)M * N * 2;  // 128 MiB
  unsigned short* A16 = (unsigned short*)d_ws;
  unsigned short* WT16 = (unsigned short*)((char*)d_ws + a_bytes);

  hipLaunchKernelGGL(convert_a_kernel, dim3(2048), dim3(256), 0, stream,
                     input, A16, (size_t)M * N / 8);
  hipLaunchKernelGGL(transpose_w_kernel, dim3(N / 32, N / 32), dim3(256), 0, stream,
                     w, WT16, N);
  hipLaunchKernelGGL(gemm256_kernel, dim3((M / 256) * (N / 256)), dim3(512), 0, stream,
                     A16, WT16, X, M, N, N);
  hipLaunchKernelGGL(lif_scan_kernel, dim3((B * N) / 256), dim3(256), 0, stream,
                     X, T, B * N);
}

// Round 3
// 714.106 us; speedup vs baseline: 1.2646x; 1.0166x over previous
//
#include <hip/hip_runtime.h>

typedef __attribute__((ext_vector_type(8))) __bf16 bf16x8;
typedef __attribute__((ext_vector_type(8))) short s16x8;
typedef __attribute__((ext_vector_type(4))) float f32x4;

__device__ __forceinline__ unsigned short f2bf(float f) {
  unsigned int u = __float_as_uint(f);
  u += 0x7FFFu + ((u >> 16) & 1u);  // RNE
  return (unsigned short)(u >> 16);
}

__device__ __forceinline__ void gload_lds16(const void* g, void* l) {
  __builtin_amdgcn_global_load_lds(
      (const __attribute__((address_space(1))) void*)g,
      (__attribute__((address_space(3))) void*)l, 16, 0, 0);
}

// raw barrier: no implicit vmcnt(0) drain (unlike __syncthreads)
__device__ __forceinline__ void bar() {
  __builtin_amdgcn_sched_barrier(0);
  asm volatile("" ::: "memory");
  __builtin_amdgcn_s_barrier();
  asm volatile("" ::: "memory");
  __builtin_amdgcn_sched_barrier(0);
}

// ---------------- conversion kernels ----------------

__global__ __launch_bounds__(256) void convert_a_kernel(
    const float* __restrict__ in, unsigned short* __restrict__ out, size_t n8) {
  size_t i = (size_t)blockIdx.x * blockDim.x + threadIdx.x;
  size_t stride = (size_t)gridDim.x * blockDim.x;
  for (; i < n8; i += stride) {
    const float4* p = (const float4*)in + 2 * i;
    float4 f0 = p[0], f1 = p[1];
    s16x8 v = {(short)f2bf(f0.x), (short)f2bf(f0.y), (short)f2bf(f0.z), (short)f2bf(f0.w),
               (short)f2bf(f1.x), (short)f2bf(f1.y), (short)f2bf(f1.z), (short)f2bf(f1.w)};
    *((s16x8*)out + i) = v;
  }
}

// wt[n][k] = w[k][n], fp32 -> bf16
__global__ __launch_bounds__(256) void transpose_w_kernel(
    const float* __restrict__ w, unsigned short* __restrict__ wt, int N) {
  __shared__ float tile[32][33];
  int bx = blockIdx.x, by = blockIdx.y;
  int tx = threadIdx.x & 31, ty = threadIdx.x >> 5;
#pragma unroll
  for (int i = 0; i < 4; ++i)
    tile[ty + 8 * i][tx] = w[(size_t)(by * 32 + ty + 8 * i) * N + bx * 32 + tx];
  __syncthreads();
#pragma unroll
  for (int i = 0; i < 4; ++i)
    wt[(size_t)(bx * 32 + ty + 8 * i) * N + by * 32 + tx] = f2bf(tile[tx][ty + 8 * i]);
}

// ---------------- GEMM 256x256, BK=64, 8 waves, per-use counted vmcnt ------
// X[M][N] = A[M][K] * B[K][N] with B given as BT[n][k] (bf16 both).
// LDS: per operand a 4-deep ring of K-half slots [256 rows][32 k] bf16 (16KB).
// Tile t reads half 2t (slot s0) at p0/p1, half 2t+1 (slot s1) at p2/p3.
// Staging in tile t: p0 -> A,B(2t+3); p2 -> A(2t+4); p3 -> B(2t+4).
// Waits: W0 (before p0 reads) vmcnt(8); W2 (before p2 reads) vmcnt(8).
// Steady invariant entering tile t: 12 outstanding = halves {2t,2t+1,2t+2}.
// Min issue->wait slack = 5 phases (~HBM latency). Last tile peeled (4/0).
// Swizzle: physical chunk p = q ^ ((r>>1)&3), both sides (rule 21).

__global__ __launch_bounds__(512, 2) void gemm256_kernel(
    const unsigned short* __restrict__ A, const unsigned short* __restrict__ Bt,
    float* __restrict__ X, int M, int N, int K) {
  __shared__ __align__(16) unsigned short Ar[4][256 * 32];
  __shared__ __align__(16) unsigned short Br[4][256 * 32];

  const int nbx = N >> 8;
  int wg = blockIdx.x;
  int nwg = gridDim.x;
  int cpx = nwg >> 3;                    // nwg % 8 == 0
  int swz = (wg & 7) * cpx + (wg >> 3);  // XCD-aware bijective swizzle
  int by = swz / nbx, bx = swz - by * nbx;
  size_t m0 = (size_t)by << 8;
  size_t n0 = (size_t)bx << 8;

  int tid = threadIdx.x;
  int lane = tid & 63;
  int wid = tid >> 6;
  int wm = wid >> 2;  // 0..1 -> A rows wm*128..+127
  int wn = wid & 3;   // 0..3 -> C cols wn*64..+63

  f32x4 acc[8][4];
#pragma unroll
  for (int m = 0; m < 8; ++m)
#pragma unroll
    for (int n = 0; n < 4; ++n) acc[m][n] = f32x4{0.f, 0.f, 0.f, 0.f};

  const int nk = K >> 6;  // BK=64 tiles

  auto stageA = [&](int H) {
    int slot = H & 3;
    int kbase = ((H >> 1) << 6) + ((H & 1) << 5);
#pragma unroll
    for (int i = 0; i < 2; ++i) {
      int s = tid + (i << 9);
      int r = s >> 2, pch = s & 3;
      int c = pch ^ ((r >> 1) & 3);
      gload_lds16(A + (m0 + r) * (size_t)K + kbase + c * 8,
                  &Ar[slot][(size_t)((wid << 6) + (i << 9)) * 8]);
    }
  };
  auto stageB = [&](int H) {
    int slot = H & 3;
    int kbase = ((H >> 1) << 6) + ((H & 1) << 5);
#pragma unroll
    for (int i = 0; i < 2; ++i) {
      int s = tid + (i << 9);
      int r = s >> 2, pch = s & 3;
      int c = pch ^ ((r >> 1) & 3);
      gload_lds16(Bt + (n0 + r) * (size_t)K + kbase + c * 8,
                  &Br[slot][(size_t)((wid << 6) + (i << 9)) * 8]);
    }
  };

  bf16x8 af[4], bf[4];
  auto rdA = [&](int slot, int mh) {
#pragma unroll
    for (int m = 0; m < 4; ++m) {
      int r = wm * 128 + (mh * 4 + m) * 16 + (lane & 15);
      int p = (lane >> 4) ^ ((r >> 1) & 3);
      af[m] = *(const bf16x8*)&Ar[slot][r * 32 + p * 8];
    }
  };
  auto rdB = [&](int slot) {
#pragma unroll
    for (int n = 0; n < 4; ++n) {
      int r = wn * 64 + n * 16 + (lane & 15);
      int p = (lane >> 4) ^ ((r >> 1) & 3);
      bf[n] = *(const bf16x8*)&Br[slot][r * 32 + p * 8];
    }
  };
  auto quad = [&](int mh) {
    asm volatile("s_waitcnt lgkmcnt(0)" ::: "memory");
    __builtin_amdgcn_sched_barrier(0);
    __builtin_amdgcn_s_setprio(1);
#pragma unroll
    for (int m = 0; m < 4; ++m)
#pragma unroll
      for (int n = 0; n < 4; ++n)
        acc[mh * 4 + m][n] =
            __builtin_amdgcn_mfma_f32_16x16x32_bf16(af[m], bf[n], acc[mh * 4 + m][n], 0, 0, 0);
    __builtin_amdgcn_s_setprio(0);
  };

  // ---- prologue: stage halves 0,1,2 (12 loads in flight) ----
  stageA(0); stageB(0); stageA(1); stageB(1); stageA(2); stageB(2);

  // ---- steady tiles 0..nk-2 ----
  for (int t = 0; t < nk - 1; ++t) {
    int db = t & 1;
    int s0 = db << 1, s1 = (db << 1) | 1;
    // W0: need half 2t (oldest 4 of 12)
    asm volatile("s_waitcnt vmcnt(8)" ::: "memory");
    bar();
    // p0
    rdA(s0, 0);
    rdB(s0);
    stageA(2 * t + 3);
    stageB(2 * t + 3);
    quad(0);
    bar();
    // p1
    rdA(s0, 1);
    quad(1);
    // W2: need half 2t+1 (oldest 4 of 12)
    asm volatile("s_waitcnt vmcnt(8)" ::: "memory");
    bar();
    // p2
    rdA(s1, 0);
    rdB(s1);
    if (t < nk - 2) stageA(2 * t + 4);
    quad(0);
    bar();
    // p3
    rdA(s1, 1);
    if (t < nk - 2) stageB(2 * t + 4);
    quad(1);
    // no boundary wait: next iteration's W0 covers it
  }

  // ---- peeled last tile (outstanding entering: 8 = halves {2nk-2, 2nk-1}) --
  {
    int t = nk - 1;
    int db = t & 1;
    int s0 = db << 1, s1 = (db << 1) | 1;
    asm volatile("s_waitcnt vmcnt(4)" ::: "memory");
    bar();
    rdA(s0, 0);
    rdB(s0);
    quad(0);
    bar();
    rdA(s0, 1);
    quad(1);
    asm volatile("s_waitcnt vmcnt(0)" ::: "memory");
    bar();
    rdA(s1, 0);
    rdB(s1);
    quad(0);
    bar();
    rdA(s1, 1);
    quad(1);
  }

  // epilogue: C/D frag layout col=lane&15, row=(lane>>4)*4+j
#pragma unroll
  for (int m = 0; m < 8; ++m) {
    size_t row = m0 + wm * 128 + m * 16 + ((lane >> 4) << 2);
#pragma unroll
    for (int n = 0; n < 4; ++n) {
      size_t col = n0 + wn * 64 + n * 16 + (lane & 15);
      float* px = X + row * (size_t)N + col;
#pragma unroll
      for (int j = 0; j < 4; ++j) px[(size_t)j * N] = acc[m][n][j];
    }
  }
}

// ---------------- LIF scan: in-place X -> spikes ----------------

__global__ __launch_bounds__(256) void lif_scan_kernel(
    float* __restrict__ XS, int T, int stride) {
  int idx = blockIdx.x * 256 + threadIdx.x;
  const float decay = 0.99004983374916811f;  // exp(-1/100) fp32
  float v = -65.0f, refrac = 0.0f;
  size_t p = (size_t)idx;
  for (int t0 = 0; t0 < T; t0 += 8) {
    float x[8];
#pragma unroll
    for (int i = 0; i < 8; ++i) x[i] = XS[p + (size_t)i * stride];
    float o[8];
#pragma unroll
    for (int i = 0; i < 8; ++i) {
      v = decay * (v + 65.0f) - 65.0f;
      if (refrac <= 0.0f) v += x[i];
      refrac = fmaxf(refrac - 1.0f, 0.0f);
      bool s = (v >= -52.0f);
      o[i] = s ? 1.0f : 0.0f;
      refrac = s ? 5.0f : refrac;
      v = s ? -65.0f : v;
    }
#pragma unroll
    for (int i = 0; i < 8; ++i) XS[p + (size_t)i * stride] = o[i];
    p += (size_t)8 * stride;
  }
}

// ---------------- launch ----------------

extern "C" void kernel_launch(void* const* d_in, const int* in_sizes, int n_in,
                              void* d_out, int out_size, void* d_ws, size_t ws_size,
                              hipStream_t stream) {
  const float* input = (const float*)d_in[0];  // [T,B,N] fp32
  const float* w = (const float*)d_in[1];      // [N,N] fp32
  const int N = 4096, T = 512, B = 32;
  const int M = T * B;  // 16384
  float* X = (float*)d_out;

  size_t a_bytes = (size_t)M * N * 2;  // 128 MiB
  unsigned short* A16 = (unsigned short*)d_ws;
  unsigned short* WT16 = (unsigned short*)((char*)d_ws + a_bytes);

  hipLaunchKernelGGL(convert_a_kernel, dim3(2048), dim3(256), 0, stream,
                     input, A16, (size_t)M * N / 8);
  hipLaunchKernelGGL(transpose_w_kernel, dim3(N / 32, N / 32), dim3(256), 0, stream,
                     w, WT16, N);
  hipLaunchKernelGGL(gemm256_kernel, dim3((M / 256) * (N / 256)), dim3(512), 0, stream,
                     A16, WT16, X, M, N, N);
  hipLaunchKernelGGL(lif_scan_kernel, dim3((B * N) / 256), dim3(256), 0, stream,
                     X, T, B * N);
}